// Round 7
// baseline (706.570 us; speedup 1.0000x reference)
//
#include <hip/hip_runtime.h>
#include <hip/hip_bf16.h>

// GeneratorSDF: latent-conditioned MLP SDF on a 128^3 grid (fp32 I/O).
// dims: 67 -> 128 -> 64 -> 32 -> 1 (relu, relu, relu, sigmoid)
//
// R7 (stall surgery; R6 was 124us @ MfmaUtil 14 / VALUBusy 56 — latency-bound):
//  - Software-pipelined h2 round-trip: A-phase(ng) writes slot ng&1, B-phase(ng-1)
//    reads slot (ng-1)&1 one iteration later => ~300 cyc of independent work sits
//    between the LDS write and its dependent read. Per-wave DS ops are in-order
//    (R6's barrier-free RAW passed), so no barriers needed.
//  - Epilogue deferred: per-quad z partials to LDS, one batched phase C with a
//    single b128 read + sigmoid + fully coalesced store (replaces 8x two serial
//    shfl_xor chains).
//  - 512 pts/block (8 ng), grid 4096: halves per-point prep amortization.
//  - LDS union: weight-staging reuses the same space as h2+z scratch (~30 KB).
//  - __launch_bounds__(256,4): force VGPR <= 128 (waves/SIMD halve at 128 — m69).
// MFMA layouts (verified m89/m91): A[m=lane&15][k=quad*8+j],
// B[k=quad*8+j][n=lane&15], C/D row=quad*4+reg, col=lane&15.

#define NPTS (128 * 128 * 128)

typedef float f32x4_t __attribute__((ext_vector_type(4)));
typedef short bf16x8_t __attribute__((ext_vector_type(8)));

__device__ __forceinline__ unsigned pk2(float lo, float hi) {
    __hip_bfloat162 p = __float22bfloat162_rn(make_float2(lo, hi));
    unsigned u;
    __builtin_memcpy(&u, &p, sizeof(u));
    return u;
}

__global__ __launch_bounds__(256, 4) void mlp_kernel(
    const float* __restrict__ x,  const float* __restrict__ W1,
    const float* __restrict__ b1, const float* __restrict__ W2,
    const float* __restrict__ b2, const float* __restrict__ W3,
    const float* __restrict__ b3, const float* __restrict__ W4,
    const float* __restrict__ b4, float* __restrict__ out) {
    __shared__ __align__(16) float2 s_d[4][128];   // per-wave {base+wa*pa+wb*pb_w, wc}
    __shared__ __align__(16) float s_b2[64];
    __shared__ __align__(16) float s_b3[32];
    __shared__ __align__(16) float s_w4[32];
    // Union (26.6 KB): staging = w2a[16][64][8] (shorts 0..8191) + w3a[4][64][8]
    // (8192..10239); runtime = h2 slots [w][2][16][72] (0..9215) + z floats
    // (shorts 9216..13311 = float[4][8][16][4] : w*512 + ng*64 + i*4 + q).
    __shared__ __align__(16) unsigned short s_u[13312];

    const int t = threadIdx.x;
    const int w = t >> 6;
    const int lane = t & 63;
    const int quad = lane >> 4;
    const int l15 = lane & 15;
    const float step = 2.0f / 127.0f;

    // ================= per-block prep =================
    if (t < 128) {
        const float* w1row = W1 + t * 67;
        float s = b1[t];
#pragma unroll 8
        for (int c = 0; c < 64; ++c) s = fmaf(w1row[c], x[c], s);
        const float wa = w1row[64], wb = w1row[65], wc = w1row[66];
        const float pa = -1.0f + step * (float)(blockIdx.x >> 5);
        const float base = fmaf(wa, pa, s);
        const int gj0 = (blockIdx.x * 4) & 127;  // multiple of 4, gj0+3 <= 127
#pragma unroll
        for (int j = 0; j < 4; ++j) {
            const float pb = -1.0f + step * (float)(gj0 + j);
            s_d[j][t] = make_float2(fmaf(wb, pb, base), wc);
        }
    }
    // W2 [64][128] -> bf16 A-frag staging
    const float2* W2v = (const float2*)W2;
#pragma unroll
    for (int it = 0; it < 16; ++it) {
        int pidx = t + 256 * it;
        int idx2 = pidx * 2;
        int o = idx2 >> 7, k = idx2 & 127;
        int mt = o >> 4, lm = o & 15;
        int kb = k >> 5, q = (k >> 3) & 3, jj = k & 7;
        float2 v = W2v[pidx];
        *(unsigned*)&s_u[(mt * 4 + kb) * 512 + (q * 16 + lm) * 8 + jj] = pk2(v.x, v.y);
    }
    // W3 [32][64] -> bf16 A-frag staging
    const float2* W3v = (const float2*)W3;
#pragma unroll
    for (int it = 0; it < 4; ++it) {
        int pidx = t + 256 * it;
        int idx2 = pidx * 2;
        int o = idx2 >> 6, k = idx2 & 63;
        int mt = o >> 4, lm = o & 15;
        int kb = k >> 5, q = (k >> 3) & 3, jj = k & 7;
        float2 v = W3v[pidx];
        *(unsigned*)&s_u[8192 + (mt * 2 + kb) * 512 + (q * 16 + lm) * 8 + jj] = pk2(v.x, v.y);
    }
    if (t < 64) s_b2[t] = b2[t];
    if (t < 32) {
        s_b3[t] = b3[t];
        s_w4[t] = W4[t];
    }
    const float bias4 = b4[0];
    __syncthreads();

    // ================= per-wave fragment preload =================
    bf16x8_t a2[16];
#pragma unroll
    for (int f = 0; f < 16; ++f) a2[f] = *(const bf16x8_t*)&s_u[f * 512 + lane * 8];
    bf16x8_t a3[4];
#pragma unroll
    for (int f = 0; f < 4; ++f) a3[f] = *(const bf16x8_t*)&s_u[8192 + f * 512 + lane * 8];
    float4 b2q[4];
#pragma unroll
    for (int mt = 0; mt < 4; ++mt) b2q[mt] = *(const float4*)&s_b2[mt * 16 + quad * 4];
    float4 b3q[2], w4q[2];
#pragma unroll
    for (int mt = 0; mt < 2; ++mt) {
        b3q[mt] = *(const float4*)&s_b3[mt * 16 + quad * 4];
        w4q[mt] = *(const float4*)&s_w4[mt * 16 + quad * 4];
    }
    __syncthreads();  // union handoff: staging -> h2/z scratch

    const float2* dj = &s_d[w][0];
    const int sw = (l15 & 1) * 32;                    // h2 channel swizzle (shorts)
    unsigned short* h2w = &s_u[w * 2 * 1152];         // 2 slots x 16 pts x 72 shorts
    float* zf = (float*)&s_u[9216];                   // [w][ng][i][q]

    // B-phase: layer 3 + w4-dot for point-group pg (reads h2 slot pg&1)
    auto bphase = [&](int pg) {
        const unsigned short* pslot = h2w + (pg & 1) * 1152 + l15 * 72;
        bf16x8_t b3f0 = *(const bf16x8_t*)&pslot[(0 ^ sw) + quad * 8];
        bf16x8_t b3f1 = *(const bf16x8_t*)&pslot[(32 ^ sw) + quad * 8];
        float z = 0.0f;
#pragma unroll
        for (int mt = 0; mt < 2; ++mt) {
            f32x4_t c;
            c[0] = b3q[mt].x; c[1] = b3q[mt].y; c[2] = b3q[mt].z; c[3] = b3q[mt].w;
            c = __builtin_amdgcn_mfma_f32_16x16x32_bf16(a3[mt * 2 + 0], b3f0, c, 0, 0, 0);
            c = __builtin_amdgcn_mfma_f32_16x16x32_bf16(a3[mt * 2 + 1], b3f1, c, 0, 0, 0);
            z = fmaf(w4q[mt].x, fmaxf(c[0], 0.0f), z);
            z = fmaf(w4q[mt].y, fmaxf(c[1], 0.0f), z);
            z = fmaf(w4q[mt].z, fmaxf(c[2], 0.0f), z);
            z = fmaf(w4q[mt].w, fmaxf(c[3], 0.0f), z);
        }
        zf[w * 512 + pg * 64 + l15 * 4 + quad] = z;  // 2-way banked (free)
    };

    // ========== pipelined main loop: A(ng) then B(ng-1) ==========
#pragma unroll 2
    for (int ng = 0; ng < 8; ++ng) {
        const float pc = fmaf(step, (float)(ng * 16 + l15), -1.0f);

        // ---- A: h1 into B-fragments (b128 dj reads) ----
        bf16x8_t bfrag[4];
#pragma unroll
        for (int kb = 0; kb < 4; ++kb) {
            union { bf16x8_t v; unsigned u[4]; } bb;
#pragma unroll
            for (int jp = 0; jp < 4; ++jp) {
                float4 dd = *(const float4*)&dj[kb * 32 + quad * 8 + 2 * jp];
                float h0 = fmaxf(fmaf(dd.y, pc, dd.x), 0.0f);
                float h1 = fmaxf(fmaf(dd.w, pc, dd.z), 0.0f);
                bb.u[jp] = pk2(h0, h1);
            }
            bfrag[kb] = bb.v;
        }
        // ---- A: layer 2 MFMA, bias in C-init ----
        f32x4_t acc2[4];
#pragma unroll
        for (int mt = 0; mt < 4; ++mt) {
            f32x4_t c;
            c[0] = b2q[mt].x; c[1] = b2q[mt].y; c[2] = b2q[mt].z; c[3] = b2q[mt].w;
#pragma unroll
            for (int kb = 0; kb < 4; ++kb)
                c = __builtin_amdgcn_mfma_f32_16x16x32_bf16(a2[mt * 4 + kb], bfrag[kb], c, 0, 0, 0);
            acc2[mt] = c;
        }
        // ---- A: relu + pack + write h2 slot ng&1 ----
        unsigned short* slot = h2w + (ng & 1) * 1152 + l15 * 72;
#pragma unroll
        for (int mt = 0; mt < 4; ++mt) {
            uint2 pk;
            pk.x = pk2(fmaxf(acc2[mt][0], 0.0f), fmaxf(acc2[mt][1], 0.0f));
            pk.y = pk2(fmaxf(acc2[mt][2], 0.0f), fmaxf(acc2[mt][3], 0.0f));
            *(uint2*)&slot[(mt * 16 + quad * 4) ^ sw] = pk;
        }
        // ---- B for previous group (write->read distance = one full A) ----
        if (ng > 0) bphase(ng - 1);
    }
    bphase(7);  // drain

    // ========== phase C: batched reduce + sigmoid + coalesced store ==========
#pragma unroll
    for (int half = 0; half < 2; ++half) {
        const int p = lane + 64 * half;       // point within this wave's 128
        const int ng = p >> 4, i = p & 15;
        float4 v = *(const float4*)&zf[w * 512 + ng * 64 + i * 4];
        float z = (v.x + v.y) + (v.z + v.w) + bias4;
        float sig = 1.0f / (1.0f + __expf(-z));
        out[blockIdx.x * 512 + w * 128 + p] = sig;
    }
}

extern "C" void kernel_launch(void* const* d_in, const int* in_sizes, int n_in,
                              void* d_out, int out_size, void* d_ws, size_t ws_size,
                              hipStream_t stream) {
    mlp_kernel<<<NPTS / 512, 256, 0, stream>>>(
        (const float*)d_in[0], (const float*)d_in[1], (const float*)d_in[2],
        (const float*)d_in[3], (const float*)d_in[4], (const float*)d_in[5],
        (const float*)d_in[6], (const float*)d_in[7], (const float*)d_in[8],
        (float*)d_out);
}

// Round 8
// 147.791 us; speedup vs baseline: 4.7809x; 4.7809x over previous
//
#include <hip/hip_runtime.h>
#include <hip/hip_bf16.h>

// GeneratorSDF: latent-conditioned MLP SDF on a 128^3 grid (fp32 I/O).
// dims: 67 -> 128 -> 64 -> 32 -> 1 (relu, relu, relu, sigmoid)
//
// R8 = R7 structure with __launch_bounds__(256,2). R7's (256,4) forced
// VGPR=64 -> full working-set spill (FETCH 1.95 GB, 647us). The pipeline
// itself was never measured; this is the clean one-variable experiment.
// R7 structure recap:
//  - Software-pipelined h2 round-trip: A(ng) writes slot ng&1; B(ng-1) reads
//    the other slot => one full A-phase (~300cyc) between LDS write and read.
//  - Deferred epilogue: per-quad z partials to LDS; batched phase C does one
//    b128 read + sigmoid + fully coalesced store (no serial shfl chains).
//  - 512 pts/block (8 ng), grid 4096; per-wave pb table s_d[w].
//  - LDS union: weight staging reused as h2+z scratch (~30 KB).
// MFMA layouts (verified m89/m91): A[m=lane&15][k=quad*8+j],
// B[k=quad*8+j][n=lane&15], C/D row=quad*4+reg, col=lane&15.

#define NPTS (128 * 128 * 128)

typedef float f32x4_t __attribute__((ext_vector_type(4)));
typedef short bf16x8_t __attribute__((ext_vector_type(8)));

__device__ __forceinline__ unsigned pk2(float lo, float hi) {
    __hip_bfloat162 p = __float22bfloat162_rn(make_float2(lo, hi));
    unsigned u;
    __builtin_memcpy(&u, &p, sizeof(u));
    return u;
}

__global__ __launch_bounds__(256, 2) void mlp_kernel(
    const float* __restrict__ x,  const float* __restrict__ W1,
    const float* __restrict__ b1, const float* __restrict__ W2,
    const float* __restrict__ b2, const float* __restrict__ W3,
    const float* __restrict__ b3, const float* __restrict__ W4,
    const float* __restrict__ b4, float* __restrict__ out) {
    __shared__ __align__(16) float2 s_d[4][128];   // per-wave {base+wa*pa+wb*pb_w, wc}
    __shared__ __align__(16) float s_b2[64];
    __shared__ __align__(16) float s_b3[32];
    __shared__ __align__(16) float s_w4[32];
    // Union (26.6 KB): staging = w2a[16][64][8] (shorts 0..8191) + w3a[4][64][8]
    // (8192..10239); runtime = h2 slots [w][2][16][72] (0..9215) + z floats
    // (shorts 9216..13311 = float[4][8][16][4] : w*512 + ng*64 + i*4 + q).
    __shared__ __align__(16) unsigned short s_u[13312];

    const int t = threadIdx.x;
    const int w = t >> 6;
    const int lane = t & 63;
    const int quad = lane >> 4;
    const int l15 = lane & 15;
    const float step = 2.0f / 127.0f;

    // ================= per-block prep =================
    if (t < 128) {
        const float* w1row = W1 + t * 67;
        float s = b1[t];
#pragma unroll 8
        for (int c = 0; c < 64; ++c) s = fmaf(w1row[c], x[c], s);
        const float wa = w1row[64], wb = w1row[65], wc = w1row[66];
        const float pa = -1.0f + step * (float)(blockIdx.x >> 5);
        const float base = fmaf(wa, pa, s);
        const int gj0 = (blockIdx.x * 4) & 127;  // multiple of 4, gj0+3 <= 127
#pragma unroll
        for (int j = 0; j < 4; ++j) {
            const float pb = -1.0f + step * (float)(gj0 + j);
            s_d[j][t] = make_float2(fmaf(wb, pb, base), wc);
        }
    }
    // W2 [64][128] -> bf16 A-frag staging
    const float2* W2v = (const float2*)W2;
#pragma unroll
    for (int it = 0; it < 16; ++it) {
        int pidx = t + 256 * it;
        int idx2 = pidx * 2;
        int o = idx2 >> 7, k = idx2 & 127;
        int mt = o >> 4, lm = o & 15;
        int kb = k >> 5, q = (k >> 3) & 3, jj = k & 7;
        float2 v = W2v[pidx];
        *(unsigned*)&s_u[(mt * 4 + kb) * 512 + (q * 16 + lm) * 8 + jj] = pk2(v.x, v.y);
    }
    // W3 [32][64] -> bf16 A-frag staging
    const float2* W3v = (const float2*)W3;
#pragma unroll
    for (int it = 0; it < 4; ++it) {
        int pidx = t + 256 * it;
        int idx2 = pidx * 2;
        int o = idx2 >> 6, k = idx2 & 63;
        int mt = o >> 4, lm = o & 15;
        int kb = k >> 5, q = (k >> 3) & 3, jj = k & 7;
        float2 v = W3v[pidx];
        *(unsigned*)&s_u[8192 + (mt * 2 + kb) * 512 + (q * 16 + lm) * 8 + jj] = pk2(v.x, v.y);
    }
    if (t < 64) s_b2[t] = b2[t];
    if (t < 32) {
        s_b3[t] = b3[t];
        s_w4[t] = W4[t];
    }
    const float bias4 = b4[0];
    __syncthreads();

    // ================= per-wave fragment preload =================
    bf16x8_t a2[16];
#pragma unroll
    for (int f = 0; f < 16; ++f) a2[f] = *(const bf16x8_t*)&s_u[f * 512 + lane * 8];
    bf16x8_t a3[4];
#pragma unroll
    for (int f = 0; f < 4; ++f) a3[f] = *(const bf16x8_t*)&s_u[8192 + f * 512 + lane * 8];
    float4 b2q[4];
#pragma unroll
    for (int mt = 0; mt < 4; ++mt) b2q[mt] = *(const float4*)&s_b2[mt * 16 + quad * 4];
    float4 b3q[2], w4q[2];
#pragma unroll
    for (int mt = 0; mt < 2; ++mt) {
        b3q[mt] = *(const float4*)&s_b3[mt * 16 + quad * 4];
        w4q[mt] = *(const float4*)&s_w4[mt * 16 + quad * 4];
    }
    __syncthreads();  // union handoff: staging -> h2/z scratch

    const float2* dj = &s_d[w][0];
    const int sw = (l15 & 1) * 32;                    // h2 channel swizzle (shorts)
    unsigned short* h2w = &s_u[w * 2 * 1152];         // 2 slots x 16 pts x 72 shorts
    float* zf = (float*)&s_u[9216];                   // [w][ng][i][q]

    // B-phase: layer 3 + w4-dot for point-group pg (reads h2 slot pg&1)
    auto bphase = [&](int pg) {
        const unsigned short* pslot = h2w + (pg & 1) * 1152 + l15 * 72;
        bf16x8_t b3f0 = *(const bf16x8_t*)&pslot[(0 ^ sw) + quad * 8];
        bf16x8_t b3f1 = *(const bf16x8_t*)&pslot[(32 ^ sw) + quad * 8];
        float z = 0.0f;
#pragma unroll
        for (int mt = 0; mt < 2; ++mt) {
            f32x4_t c;
            c[0] = b3q[mt].x; c[1] = b3q[mt].y; c[2] = b3q[mt].z; c[3] = b3q[mt].w;
            c = __builtin_amdgcn_mfma_f32_16x16x32_bf16(a3[mt * 2 + 0], b3f0, c, 0, 0, 0);
            c = __builtin_amdgcn_mfma_f32_16x16x32_bf16(a3[mt * 2 + 1], b3f1, c, 0, 0, 0);
            z = fmaf(w4q[mt].x, fmaxf(c[0], 0.0f), z);
            z = fmaf(w4q[mt].y, fmaxf(c[1], 0.0f), z);
            z = fmaf(w4q[mt].z, fmaxf(c[2], 0.0f), z);
            z = fmaf(w4q[mt].w, fmaxf(c[3], 0.0f), z);
        }
        zf[w * 512 + pg * 64 + l15 * 4 + quad] = z;  // 2-way banked (free)
    };

    // ========== pipelined main loop: A(ng) then B(ng-1) ==========
#pragma unroll 2
    for (int ng = 0; ng < 8; ++ng) {
        const float pc = fmaf(step, (float)(ng * 16 + l15), -1.0f);

        // ---- A: h1 into B-fragments (b128 dj reads) ----
        bf16x8_t bfrag[4];
#pragma unroll
        for (int kb = 0; kb < 4; ++kb) {
            union { bf16x8_t v; unsigned u[4]; } bb;
#pragma unroll
            for (int jp = 0; jp < 4; ++jp) {
                float4 dd = *(const float4*)&dj[kb * 32 + quad * 8 + 2 * jp];
                float h0 = fmaxf(fmaf(dd.y, pc, dd.x), 0.0f);
                float h1 = fmaxf(fmaf(dd.w, pc, dd.z), 0.0f);
                bb.u[jp] = pk2(h0, h1);
            }
            bfrag[kb] = bb.v;
        }
        // ---- A: layer 2 MFMA, bias in C-init ----
        f32x4_t acc2[4];
#pragma unroll
        for (int mt = 0; mt < 4; ++mt) {
            f32x4_t c;
            c[0] = b2q[mt].x; c[1] = b2q[mt].y; c[2] = b2q[mt].z; c[3] = b2q[mt].w;
#pragma unroll
            for (int kb = 0; kb < 4; ++kb)
                c = __builtin_amdgcn_mfma_f32_16x16x32_bf16(a2[mt * 4 + kb], bfrag[kb], c, 0, 0, 0);
            acc2[mt] = c;
        }
        // ---- A: relu + pack + write h2 slot ng&1 ----
        unsigned short* slot = h2w + (ng & 1) * 1152 + l15 * 72;
#pragma unroll
        for (int mt = 0; mt < 4; ++mt) {
            uint2 pk;
            pk.x = pk2(fmaxf(acc2[mt][0], 0.0f), fmaxf(acc2[mt][1], 0.0f));
            pk.y = pk2(fmaxf(acc2[mt][2], 0.0f), fmaxf(acc2[mt][3], 0.0f));
            *(uint2*)&slot[(mt * 16 + quad * 4) ^ sw] = pk;
        }
        // ---- B for previous group (write->read distance = one full A) ----
        if (ng > 0) bphase(ng - 1);
    }
    bphase(7);  // drain

    // ========== phase C: batched reduce + sigmoid + coalesced store ==========
#pragma unroll
    for (int half = 0; half < 2; ++half) {
        const int p = lane + 64 * half;       // point within this wave's 128
        const int ng = p >> 4, i = p & 15;
        float4 v = *(const float4*)&zf[w * 512 + ng * 64 + i * 4];
        float z = (v.x + v.y) + (v.z + v.w) + bias4;
        float sig = 1.0f / (1.0f + __expf(-z));
        out[blockIdx.x * 512 + w * 128 + p] = sig;
    }
}

extern "C" void kernel_launch(void* const* d_in, const int* in_sizes, int n_in,
                              void* d_out, int out_size, void* d_ws, size_t ws_size,
                              hipStream_t stream) {
    mlp_kernel<<<NPTS / 512, 256, 0, stream>>>(
        (const float*)d_in[0], (const float*)d_in[1], (const float*)d_in[2],
        (const float*)d_in[3], (const float*)d_in[4], (const float*)d_in[5],
        (const float*)d_in[6], (const float*)d_in[7], (const float*)d_in[8],
        (float*)d_out);
}

// Round 9
// 147.347 us; speedup vs baseline: 4.7953x; 1.0030x over previous
//
#include <hip/hip_runtime.h>
#include <hip/hip_bf16.h>

// GeneratorSDF: latent-conditioned MLP SDF on a 128^3 grid (fp32 I/O).
// dims: 67 -> 128 -> 64 -> 32 -> 1 (relu, relu, relu, sigmoid)
//
// R9 = R8 + packed-fp32 VALU (V_PK_FMA_F32 / V_PK_MAX_F32 via
// __builtin_elementwise_* on float2). R8: 93.6us @ MfmaUtil 19.4 / VALUBusy 65;
// h1-build was ~55% of VALU instrs. SoA d-tables (s_base / s_wc) put pair
// operands in adjacent regs so VOP3P forms. Pack & B-phase dots pk'd too.
// Structure from R8 (verified): software-pipelined h2 double-buffer (A(ng)
// writes slot ng&1, B(ng-1) reads other slot), deferred batched epilogue,
// 512 pts/block, LDS union, __launch_bounds__(256,2) (R7 lesson: (256,4)
// forces VGPR=64 -> total spill).
// MFMA layouts (verified m89/m91): A[m=lane&15][k=quad*8+j],
// B[k=quad*8+j][n=lane&15], C/D row=quad*4+reg, col=lane&15.

#define NPTS (128 * 128 * 128)

typedef float f32x4_t __attribute__((ext_vector_type(4)));
typedef float f32x2_t __attribute__((ext_vector_type(2)));
typedef short bf16x8_t __attribute__((ext_vector_type(8)));

__device__ __forceinline__ unsigned pk2(float lo, float hi) {
    __hip_bfloat162 p = __float22bfloat162_rn(make_float2(lo, hi));
    unsigned u;
    __builtin_memcpy(&u, &p, sizeof(u));
    return u;
}

__global__ __launch_bounds__(256, 2) void mlp_kernel(
    const float* __restrict__ x,  const float* __restrict__ W1,
    const float* __restrict__ b1, const float* __restrict__ W2,
    const float* __restrict__ b2, const float* __restrict__ W3,
    const float* __restrict__ b3, const float* __restrict__ W4,
    const float* __restrict__ b4, float* __restrict__ out) {
    __shared__ __align__(16) float s_base[4][128];  // per-wave j: base+wa*pa+wb*pb_j
    __shared__ __align__(16) float s_wc[128];       // wc[k] (j-independent)
    __shared__ __align__(16) float s_b2[64];
    __shared__ __align__(16) float s_b3[32];
    __shared__ __align__(16) float s_w4[32];
    // Union (26.6 KB): staging = w2a[16][64][8] (shorts 0..8191) + w3a[4][64][8]
    // (8192..10239); runtime = h2 slots [w][2][16][72] (0..9215) + z floats
    // (shorts 9216..13311 = float[4][8][16][4] : w*512 + ng*64 + i*4 + q).
    __shared__ __align__(16) unsigned short s_u[13312];

    const int t = threadIdx.x;
    const int w = t >> 6;
    const int lane = t & 63;
    const int quad = lane >> 4;
    const int l15 = lane & 15;
    const float step = 2.0f / 127.0f;

    // ================= per-block prep =================
    if (t < 128) {
        const float* w1row = W1 + t * 67;
        float s = b1[t];
#pragma unroll 8
        for (int c = 0; c < 64; ++c) s = fmaf(w1row[c], x[c], s);
        const float wa = w1row[64], wb = w1row[65], wc = w1row[66];
        const float pa = -1.0f + step * (float)(blockIdx.x >> 5);
        const float base = fmaf(wa, pa, s);
        const int gj0 = (blockIdx.x * 4) & 127;  // multiple of 4, gj0+3 <= 127
        s_wc[t] = wc;
#pragma unroll
        for (int j = 0; j < 4; ++j) {
            const float pb = -1.0f + step * (float)(gj0 + j);
            s_base[j][t] = fmaf(wb, pb, base);
        }
    }
    // W2 [64][128] -> bf16 A-frag staging
    const float2* W2v = (const float2*)W2;
#pragma unroll
    for (int it = 0; it < 16; ++it) {
        int pidx = t + 256 * it;
        int idx2 = pidx * 2;
        int o = idx2 >> 7, k = idx2 & 127;
        int mt = o >> 4, lm = o & 15;
        int kb = k >> 5, q = (k >> 3) & 3, jj = k & 7;
        float2 v = W2v[pidx];
        *(unsigned*)&s_u[(mt * 4 + kb) * 512 + (q * 16 + lm) * 8 + jj] = pk2(v.x, v.y);
    }
    // W3 [32][64] -> bf16 A-frag staging
    const float2* W3v = (const float2*)W3;
#pragma unroll
    for (int it = 0; it < 4; ++it) {
        int pidx = t + 256 * it;
        int idx2 = pidx * 2;
        int o = idx2 >> 6, k = idx2 & 63;
        int mt = o >> 4, lm = o & 15;
        int kb = k >> 5, q = (k >> 3) & 3, jj = k & 7;
        float2 v = W3v[pidx];
        *(unsigned*)&s_u[8192 + (mt * 2 + kb) * 512 + (q * 16 + lm) * 8 + jj] = pk2(v.x, v.y);
    }
    if (t < 64) s_b2[t] = b2[t];
    if (t < 32) {
        s_b3[t] = b3[t];
        s_w4[t] = W4[t];
    }
    const float bias4 = b4[0];
    __syncthreads();

    // ================= per-wave fragment preload =================
    bf16x8_t a2[16];
#pragma unroll
    for (int f = 0; f < 16; ++f) a2[f] = *(const bf16x8_t*)&s_u[f * 512 + lane * 8];
    bf16x8_t a3[4];
#pragma unroll
    for (int f = 0; f < 4; ++f) a3[f] = *(const bf16x8_t*)&s_u[8192 + f * 512 + lane * 8];
    float4 b2q[4];
#pragma unroll
    for (int mt = 0; mt < 4; ++mt) b2q[mt] = *(const float4*)&s_b2[mt * 16 + quad * 4];
    float4 b3q[2];
    f32x2_t w4lo[2], w4hi[2];
#pragma unroll
    for (int mt = 0; mt < 2; ++mt) {
        b3q[mt] = *(const float4*)&s_b3[mt * 16 + quad * 4];
        float4 wq = *(const float4*)&s_w4[mt * 16 + quad * 4];
        w4lo[mt][0] = wq.x; w4lo[mt][1] = wq.y;
        w4hi[mt][0] = wq.z; w4hi[mt][1] = wq.w;
    }
    __syncthreads();  // union handoff: staging -> h2/z scratch

    const float* bj = &s_base[w][0];
    const int sw = (l15 & 1) * 32;                    // h2 channel swizzle (shorts)
    unsigned short* h2w = &s_u[w * 2 * 1152];         // 2 slots x 16 pts x 72 shorts
    float* zf = (float*)&s_u[9216];                   // [w][ng][i][q]
    const f32x2_t zero2 = {0.0f, 0.0f};

    // B-phase: layer 3 + w4-dot for point-group pg (reads h2 slot pg&1)
    auto bphase = [&](int pg) {
        const unsigned short* pslot = h2w + (pg & 1) * 1152 + l15 * 72;
        bf16x8_t b3f0 = *(const bf16x8_t*)&pslot[(0 ^ sw) + quad * 8];
        bf16x8_t b3f1 = *(const bf16x8_t*)&pslot[(32 ^ sw) + quad * 8];
        f32x2_t z2 = zero2;
#pragma unroll
        for (int mt = 0; mt < 2; ++mt) {
            f32x4_t c;
            c[0] = b3q[mt].x; c[1] = b3q[mt].y; c[2] = b3q[mt].z; c[3] = b3q[mt].w;
            c = __builtin_amdgcn_mfma_f32_16x16x32_bf16(a3[mt * 2 + 0], b3f0, c, 0, 0, 0);
            c = __builtin_amdgcn_mfma_f32_16x16x32_bf16(a3[mt * 2 + 1], b3f1, c, 0, 0, 0);
            f32x2_t h01 = __builtin_elementwise_max((f32x2_t){c[0], c[1]}, zero2);
            f32x2_t h23 = __builtin_elementwise_max((f32x2_t){c[2], c[3]}, zero2);
            z2 = __builtin_elementwise_fma(w4lo[mt], h01, z2);
            z2 = __builtin_elementwise_fma(w4hi[mt], h23, z2);
        }
        zf[w * 512 + pg * 64 + l15 * 4 + quad] = z2[0] + z2[1];
    };

    // ========== pipelined main loop: A(ng) then B(ng-1) ==========
#pragma unroll 2
    for (int ng = 0; ng < 8; ++ng) {
        const float pc = fmaf(step, (float)(ng * 16 + l15), -1.0f);
        const f32x2_t pc2 = {pc, pc};

        // ---- A: h1 into B-fragments via packed fma/max (SoA b128 reads) ----
        bf16x8_t bfrag[4];
#pragma unroll
        for (int kb = 0; kb < 4; ++kb) {
            union { bf16x8_t v; unsigned u[4]; } bb;
#pragma unroll
            for (int half = 0; half < 2; ++half) {
                const int o = kb * 32 + quad * 8 + half * 4;
                float4 bs = *(const float4*)&bj[o];
                float4 wc4 = *(const float4*)&s_wc[o];
                f32x2_t h01 = __builtin_elementwise_fma(
                    (f32x2_t){wc4.x, wc4.y}, pc2, (f32x2_t){bs.x, bs.y});
                f32x2_t h23 = __builtin_elementwise_fma(
                    (f32x2_t){wc4.z, wc4.w}, pc2, (f32x2_t){bs.z, bs.w});
                h01 = __builtin_elementwise_max(h01, zero2);
                h23 = __builtin_elementwise_max(h23, zero2);
                bb.u[half * 2 + 0] = pk2(h01[0], h01[1]);
                bb.u[half * 2 + 1] = pk2(h23[0], h23[1]);
            }
            bfrag[kb] = bb.v;
        }
        // ---- A: layer 2 MFMA, bias in C-init ----
        f32x4_t acc2[4];
#pragma unroll
        for (int mt = 0; mt < 4; ++mt) {
            f32x4_t c;
            c[0] = b2q[mt].x; c[1] = b2q[mt].y; c[2] = b2q[mt].z; c[3] = b2q[mt].w;
#pragma unroll
            for (int kb = 0; kb < 4; ++kb)
                c = __builtin_amdgcn_mfma_f32_16x16x32_bf16(a2[mt * 4 + kb], bfrag[kb], c, 0, 0, 0);
            acc2[mt] = c;
        }
        // ---- A: packed relu + pack + write h2 slot ng&1 ----
        unsigned short* slot = h2w + (ng & 1) * 1152 + l15 * 72;
#pragma unroll
        for (int mt = 0; mt < 4; ++mt) {
            f32x2_t v01 = __builtin_elementwise_max((f32x2_t){acc2[mt][0], acc2[mt][1]}, zero2);
            f32x2_t v23 = __builtin_elementwise_max((f32x2_t){acc2[mt][2], acc2[mt][3]}, zero2);
            uint2 pk;
            pk.x = pk2(v01[0], v01[1]);
            pk.y = pk2(v23[0], v23[1]);
            *(uint2*)&slot[(mt * 16 + quad * 4) ^ sw] = pk;
        }
        // ---- B for previous group (write->read distance = one full A) ----
        if (ng > 0) bphase(ng - 1);
    }
    bphase(7);  // drain

    // ========== phase C: batched reduce + sigmoid + coalesced store ==========
#pragma unroll
    for (int half = 0; half < 2; ++half) {
        const int p = lane + 64 * half;       // point within this wave's 128
        const int ng = p >> 4, i = p & 15;
        float4 v = *(const float4*)&zf[w * 512 + ng * 64 + i * 4];
        float z = (v.x + v.y) + (v.z + v.w) + bias4;
        float sig = 1.0f / (1.0f + __expf(-z));
        out[blockIdx.x * 512 + w * 128 + p] = sig;
    }
}

extern "C" void kernel_launch(void* const* d_in, const int* in_sizes, int n_in,
                              void* d_out, int out_size, void* d_ws, size_t ws_size,
                              hipStream_t stream) {
    mlp_kernel<<<NPTS / 512, 256, 0, stream>>>(
        (const float*)d_in[0], (const float*)d_in[1], (const float*)d_in[2],
        (const float*)d_in[3], (const float*)d_in[4], (const float*)d_in[5],
        (const float*)d_in[6], (const float*)d_in[7], (const float*)d_in[8],
        (float*)d_out);
}